// Round 7
// baseline (206.329 us; speedup 1.0000x reference)
//
#include <hip/hip_runtime.h>

// Problem constants (WLN_Edit): B=64, N=512, NB=600, A=89, E=5, H=256, MAX_NB=10, DEPTH=3
constexpr int Bb   = 64;
constexpr int Nn   = 512;
constexpr int NBb  = 600;
constexpr int Ad   = 89;
constexpr int Ed   = 5;
constexpr int Hd   = 256;
constexpr int MNB  = 10;
constexpr int Mrows  = Bb * Nn;    // 32768
constexpr int NBrows = Bb * NBb;   // 38400
constexpr int Kpad   = 96;

typedef __bf16 bf16x8 __attribute__((ext_vector_type(8)));
typedef float  f32x4  __attribute__((ext_vector_type(4)));

typedef __attribute__((address_space(1))) const void gvoid_t;
typedef __attribute__((address_space(3))) void lvoid_t;

__device__ inline ushort bf_rne(float x) {
  unsigned u = __float_as_uint(x);
  unsigned r = (u + 0x7fffu + ((u >> 16) & 1u)) >> 16;
  return (ushort)r;
}
__device__ inline float bf_f(ushort h) { return __uint_as_float(((unsigned)h) << 16); }

// ---------------------------------------------------------------------------
// Mega-prep: one launch, sections by blockIdx.x.
//  S0: input_atom -> Apadh (single bf16, padded [32768][96])
//  S1: Z[b,i,h] = input_bond@W_U2[256:] + b_U2 (bf16)
//  S2: PIdx[m*10+k] = (ai<<16)|bi
//  S3: w2h/w1ah/w1bh: bf16 weight panels transposed [n][k]
//  S4: Wcomb = W_atom @ {W2a, W1a} -> hi/lo bf16 transposed+padded [256][96]
//      (LDS-staged W_atom j-tiles + 4 independent acc chains — the round-6
//       version was a 96-block latency tail at ~35 µs)
// ---------------------------------------------------------------------------
constexpr int S0 = Mrows * Kpad / 256;   // 12288
constexpr int S1 = NBrows / 8;           // 4800
constexpr int S2 = Mrows * MNB / 256;    // 1280
constexpr int S3 = 256;
constexpr int S4 = Hd * Kpad / 256;      // 96

__global__ __launch_bounds__(256)
void megaprep(const float* __restrict__ input_atom, const float* __restrict__ input_bond,
              const int* __restrict__ atom_graph, const int* __restrict__ bond_graph,
              const float* __restrict__ W_atom, const float* __restrict__ W_U2,
              const float* __restrict__ b_U2, const float* __restrict__ W_U1,
              ushort* __restrict__ Apadh, ushort* __restrict__ Z, uint* __restrict__ PIdx,
              ushort* __restrict__ w2h, ushort* __restrict__ w1ah, ushort* __restrict__ w1bh,
              ushort* __restrict__ w2ch, ushort* __restrict__ w2cl,
              ushort* __restrict__ w1ch, ushort* __restrict__ w1cl) {
  __shared__ float wa[Kpad][65];                    // j-tile of W_atom, pad->bank-free
  const int blk = blockIdx.x;
  const int tid = threadIdx.x;
  if (blk < S0) {                                   // conv_atom
    const int e = blk * 256 + tid;
    const int m = e / Kpad, c = e - m * Kpad;
    Apadh[e] = bf_rne(c < Ad ? input_atom[(size_t)m * Ad + c] : 0.f);
  } else if (blk < S0 + S1) {                       // zprep
    const int r0 = (blk - S0) * 8;
    const int h = tid;
    float w[Ed];
#pragma unroll
    for (int e = 0; e < Ed; ++e) w[e] = W_U2[(size_t)(Hd + e) * Hd + h];
    const float b2 = b_U2[h];
#pragma unroll
    for (int j = 0; j < 8; ++j) {
      const int r = r0 + j;
      const float* bp = input_bond + (size_t)r * Ed;
      float d = b2;
#pragma unroll
      for (int e = 0; e < Ed; ++e) d = fmaf(bp[e], w[e], d);
      Z[(size_t)r * Hd + h] = bf_rne(d);
    }
  } else if (blk < S0 + S1 + S2) {                  // idxpack
    const int i = (blk - S0 - S1) * 256 + tid;
    const uint ai = (uint)atom_graph[(size_t)i * 2 + 1];
    const uint bi = (uint)bond_graph[(size_t)i * 2 + 1];
    PIdx[i] = (ai << 16) | bi;
  } else if (blk < S0 + S1 + S2 + S3) {             // transposed weight panels
    const int n = blk - S0 - S1 - S2;
    const int k = tid;
    const size_t o = (size_t)n * 256 + k;
    w2h[o]  = bf_rne(W_U2[(size_t)k * Hd + n]);
    w1ah[o] = bf_rne(W_U1[(size_t)k * Hd + n]);
    w1bh[o] = bf_rne(W_U1[(size_t)(k + 256) * Hd + n]);
  } else {                                          // S4': Wcomb via LDS tiles
    const int e = (blk - S0 - S1 - S2 - S3) * 256 + tid;   // e = n*96+k
    const int n = e / Kpad, k = e - n * Kpad;
    float s2a[4] = {}, s1a[4] = {};
    for (int jt = 0; jt < 4; ++jt) {                // j-tiles of 64
      for (int i = tid; i < Kpad * 64; i += 256) {  // stage (coalesced rows)
        const int r = i >> 6, c = i & 63;
        wa[r][c] = (r < Ad) ? W_atom[(size_t)r * Hd + jt * 64 + c] : 0.f;
      }
      __syncthreads();
#pragma unroll 4
      for (int jj = 0; jj < 64; ++jj) {             // 4 independent acc chains
        const int j = jt * 64 + jj;
        const float a = wa[k][jj];
        s2a[jj & 3] = fmaf(a, W_U2[(size_t)j * Hd + n], s2a[jj & 3]);
        s1a[jj & 3] = fmaf(a, W_U1[(size_t)j * Hd + n], s1a[jj & 3]);
      }
      __syncthreads();
    }
    const float s2 = (s2a[0] + s2a[1]) + (s2a[2] + s2a[3]);
    const float s1 = (s1a[0] + s1a[1]) + (s1a[2] + s1a[3]);
    ushort h = bf_rne(s2); w2ch[e] = h; w2cl[e] = bf_rne(s2 - bf_f(h));
    h = bf_rne(s1);        w1ch[e] = h; w1cl[e] = bf_rne(s1 - bf_f(h));
  }
}

// ---------------------------------------------------------------------------
// Fused TU GEMM: T = sum_seg A@Bt^T (bf16 out), P = sum_seg A@Bp^T + b_U1 (bf16).
// BM=128, BN=64, BK=32, 4 waves, 2-phase double-buffered, 1 barrier/K-step.
// ---------------------------------------------------------------------------
struct TUSegs { const ushort* a[2]; const ushort* bt[2]; const ushort* bp[2]; };

template<int NSEG, int KD>
__global__ __launch_bounds__(256)
void gemm_tu(TUSegs segs, const float* __restrict__ bias,
             ushort* __restrict__ Tout, ushort* __restrict__ Pout) {
  constexpr int NK = KD / 32;
  constexpr int TS = NSEG * NK;
  __shared__ ushort As[2][4096];
  __shared__ ushort Bt[2][2048];
  __shared__ ushort Bp[2][2048];
  const int tid  = threadIdx.x;
  const int lane = tid & 63;
  const int w    = tid >> 6;
  const int wr   = w >> 1, wc = w & 1;
  const int m0   = blockIdx.x * 128;
  const int n0   = blockIdx.y * 64;
  const int arow = tid >> 2;
  const int acol = (tid & 3) * 8;
  const int fr   = lane & 15;
  const int fq   = lane >> 4;

  f32x4 accT[4][2] = {};
  f32x4 accP[4][2] = {};

  auto stage = [&](const ushort* Aseg, const ushort* Bts, const ushort* Bps,
                   int kk, int db) {
#pragma unroll
    for (int i = 0; i < 2; ++i) {
      const ushort* ga = Aseg + (size_t)(m0 + arow + 64 * i) * KD + kk + acol;
      __builtin_amdgcn_global_load_lds((gvoid_t*)ga,
          (lvoid_t*)(&As[db][i * 2048 + w * 512]), 16, 0, 0);
    }
    const ushort* gt = Bts + (size_t)(n0 + arow) * KD + kk + acol;
    __builtin_amdgcn_global_load_lds((gvoid_t*)gt,
        (lvoid_t*)(&Bt[db][w * 512]), 16, 0, 0);
    const ushort* gp = Bps + (size_t)(n0 + arow) * KD + kk + acol;
    __builtin_amdgcn_global_load_lds((gvoid_t*)gp,
        (lvoid_t*)(&Bp[db][w * 512]), 16, 0, 0);
  };

  stage(segs.a[0], segs.bt[0], segs.bp[0], 0, 0);
  __syncthreads();

#pragma unroll
  for (int ts = 0; ts < TS; ++ts) {
    const int db = ts & 1;
    if (ts + 1 < TS) {
      const int s2 = (ts + 1) / NK;
      const int k2 = (ts + 1) % NK;
      stage(segs.a[s2], segs.bt[s2], segs.bp[s2], k2 * 32, db ^ 1);
    }
    bf16x8 bt_[2], bp_[2];
#pragma unroll
    for (int nf = 0; nf < 2; ++nf) {
      bt_[nf] = *reinterpret_cast<const bf16x8*>(&Bt[db][(wc * 32 + nf * 16 + fr) * 32 + fq * 8]);
      bp_[nf] = *reinterpret_cast<const bf16x8*>(&Bp[db][(wc * 32 + nf * 16 + fr) * 32 + fq * 8]);
    }
#pragma unroll
    for (int mf = 0; mf < 4; ++mf) {
      bf16x8 af = *reinterpret_cast<const bf16x8*>(&As[db][(wr * 64 + mf * 16 + fr) * 32 + fq * 8]);
#pragma unroll
      for (int nf = 0; nf < 2; ++nf) {
        accT[mf][nf] = __builtin_amdgcn_mfma_f32_16x16x32_bf16(af, bt_[nf], accT[mf][nf], 0, 0, 0);
        accP[mf][nf] = __builtin_amdgcn_mfma_f32_16x16x32_bf16(af, bp_[nf], accP[mf][nf], 0, 0, 0);
      }
    }
    __syncthreads();
  }

#pragma unroll
  for (int mf = 0; mf < 4; ++mf) {
#pragma unroll
    for (int nf = 0; nf < 2; ++nf) {
      const int col = n0 + wc * 32 + nf * 16 + fr;
      const float bv = bias[col];
#pragma unroll
      for (int r = 0; r < 4; ++r) {
        const int row = m0 + wr * 64 + mf * 16 + fq * 4 + r;
        Tout[(size_t)row * Hd + col] = bf_rne(accT[mf][nf][r]);
        Pout[(size_t)row * Hd + col] = bf_rne(accP[mf][nf][r] + bv);
      }
    }
  }
}

// ---------------------------------------------------------------------------
// MFMA GEMM (128x128, 4 waves): C = op( sum_seg A_seg @ B_seg^T [+ Pin] )
// OUTMODE: 0 = fp32 to Cf; 2 = bf16 to Chi.  CLOAD: add bf16 Pin tile.
// ---------------------------------------------------------------------------
struct SegPtrs { const ushort* a[2]; const ushort* b[2]; };

template<int NSEG, int KD, int OUTMODE, bool RELU, bool BIAS, bool CLOAD>
__global__ __launch_bounds__(256)
void gemm_mfma(SegPtrs segs, const float* __restrict__ bias,
               const ushort* __restrict__ Pin,
               float* __restrict__ Cf, ushort* __restrict__ Chi) {
  constexpr int NK = KD / 32;
  constexpr int TS = NSEG * NK;
  __shared__ ushort As[2][4096];
  __shared__ ushort Bs[2][4096];
  const int tid  = threadIdx.x;
  const int lane = tid & 63;
  const int w    = tid >> 6;
  const int wr   = w >> 1, wc = w & 1;
  const int m0   = blockIdx.x * 128;
  const int n0   = blockIdx.y * 128;
  const int arow = tid >> 2;
  const int acol = (tid & 3) * 8;
  const int fr   = lane & 15;
  const int fq   = lane >> 4;

  f32x4 acc[4][4] = {};

  auto stage = [&](const ushort* Aseg, const ushort* Bseg, int kk, int db) {
#pragma unroll
    for (int i = 0; i < 2; ++i) {
      const ushort* ga = Aseg + (size_t)(m0 + arow + 64 * i) * KD + kk + acol;
      const ushort* gb = Bseg + (size_t)(n0 + arow + 64 * i) * KD + kk + acol;
      __builtin_amdgcn_global_load_lds((gvoid_t*)ga,
          (lvoid_t*)(&As[db][i * 2048 + w * 512]), 16, 0, 0);
      __builtin_amdgcn_global_load_lds((gvoid_t*)gb,
          (lvoid_t*)(&Bs[db][i * 2048 + w * 512]), 16, 0, 0);
    }
  };

  stage(segs.a[0], segs.b[0], 0, 0);
  __syncthreads();

#pragma unroll
  for (int ts = 0; ts < TS; ++ts) {
    const int db = ts & 1;
    if (ts + 1 < TS) {
      const int s2 = (ts + 1) / NK;
      const int k2 = (ts + 1) % NK;
      stage(segs.a[s2], segs.b[s2], k2 * 32, db ^ 1);
    }
    bf16x8 bfr[4];
#pragma unroll
    for (int nf = 0; nf < 4; ++nf)
      bfr[nf] = *reinterpret_cast<const bf16x8*>(&Bs[db][(wc * 64 + nf * 16 + fr) * 32 + fq * 8]);
#pragma unroll
    for (int mf = 0; mf < 4; ++mf) {
      bf16x8 af = *reinterpret_cast<const bf16x8*>(&As[db][(wr * 64 + mf * 16 + fr) * 32 + fq * 8]);
#pragma unroll
      for (int nf = 0; nf < 4; ++nf)
        acc[mf][nf] = __builtin_amdgcn_mfma_f32_16x16x32_bf16(af, bfr[nf], acc[mf][nf], 0, 0, 0);
    }
    __syncthreads();
  }

#pragma unroll
  for (int mf = 0; mf < 4; ++mf) {
#pragma unroll
    for (int nf = 0; nf < 4; ++nf) {
      const int col = n0 + wc * 64 + nf * 16 + fr;
      float bv = 0.f;
      if constexpr (BIAS) bv = bias[col];
#pragma unroll
      for (int r = 0; r < 4; ++r) {
        const int row = m0 + wr * 64 + mf * 16 + fq * 4 + r;
        float v = acc[mf][nf][r] + bv;
        if constexpr (CLOAD) v += bf_f(Pin[(size_t)row * Hd + col]);
        if constexpr (RELU) v = fmaxf(v, 0.f);
        const size_t o = (size_t)row * Hd + col;
        if constexpr (OUTMODE == 0) Cf[o] = v;
        else                        Chi[o] = bf_rne(v);
      }
    }
  }
}

// ---------------------------------------------------------------------------
// nei: NEI[m,h] = sum_{k<nn} relu(T[ai[k]] + Z[bi[k]]), packed indices,
// h-oct threads (uint4 loads), 5+5 neighbor chunks. 8 rows/block.
// ---------------------------------------------------------------------------
__global__ __launch_bounds__(256)
void nei_z(const ushort* __restrict__ T, const ushort* __restrict__ Z,
           const uint* __restrict__ PIdx, const int* __restrict__ num_nbs,
           ushort* __restrict__ NEI) {
  const int ho = threadIdx.x & 31;
  const int rp = threadIdx.x >> 5;
  int bid = blockIdx.x;
  bid = (bid & 7) * (gridDim.x >> 3) + (bid >> 3);   // XCD swizzle (4096%8==0)
  const int m = bid * 8 + rp;
  const int b = m >> 9;
  const int h0 = ho * 8;
  const int nn = num_nbs[m];

  uint pk[MNB];
#pragma unroll
  for (int q = 0; q < 5; ++q) {
    const uint2 u = *reinterpret_cast<const uint2*>(&PIdx[(size_t)m * MNB + q * 2]);
    pk[q * 2] = u.x; pk[q * 2 + 1] = u.y;
  }
  int ai[MNB], bi[MNB];
#pragma unroll
  for (int k = 0; k < MNB; ++k) { ai[k] = (int)(pk[k] >> 16); bi[k] = (int)(pk[k] & 0xffffu); }
#pragma unroll
  for (int k = 1; k < MNB; ++k) {
    ai[k] = (k < nn) ? ai[k] : ai[0];
    bi[k] = (k < nn) ? bi[k] : bi[0];
  }

  float acc[8] = {};
#pragma unroll
  for (int ch = 0; ch < 2; ++ch) {
    uint4 tv[5], zv[5];
#pragma unroll
    for (int k5 = 0; k5 < 5; ++k5) {
      const int k = ch * 5 + k5;
      tv[k5] = *reinterpret_cast<const uint4*>(&T[(((size_t)b << 9) + ai[k]) * Hd + h0]);
      zv[k5] = *reinterpret_cast<const uint4*>(&Z[((size_t)b * NBb + bi[k]) * Hd + h0]);
    }
#pragma unroll
    for (int k5 = 0; k5 < 5; ++k5) {
      const int k = ch * 5 + k5;
      const uint tw[4] = {tv[k5].x, tv[k5].y, tv[k5].z, tv[k5].w};
      const uint zw[4] = {zv[k5].x, zv[k5].y, zv[k5].z, zv[k5].w};
      if (k < nn) {
#pragma unroll
        for (int q = 0; q < 4; ++q) {
          acc[q * 2]     += fmaxf(__uint_as_float(tw[q] << 16) + __uint_as_float(zw[q] << 16), 0.f);
          acc[q * 2 + 1] += fmaxf(__uint_as_float(tw[q] & 0xffff0000u) + __uint_as_float(zw[q] & 0xffff0000u), 0.f);
        }
      }
    }
  }
  uint4 o;
  o.x = (uint)bf_rne(acc[0]) | ((uint)bf_rne(acc[1]) << 16);
  o.y = (uint)bf_rne(acc[2]) | ((uint)bf_rne(acc[3]) << 16);
  o.z = (uint)bf_rne(acc[4]) | ((uint)bf_rne(acc[5]) << 16);
  o.w = (uint)bf_rne(acc[6]) | ((uint)bf_rne(acc[7]) << 16);
  *reinterpret_cast<uint4*>(&NEI[(size_t)m * Hd + h0]) = o;
}

extern "C" void kernel_launch(void* const* d_in, const int* in_sizes, int n_in,
                              void* d_out, int out_size, void* d_ws, size_t ws_size,
                              hipStream_t stream) {
  const float* input_atom = (const float*)d_in[0];
  const float* input_bond = (const float*)d_in[1];
  const int*   atom_graph = (const int*)d_in[2];
  const int*   bond_graph = (const int*)d_in[3];
  const int*   num_nbs    = (const int*)d_in[4];
  const float* W_atom     = (const float*)d_in[5];
  const float* W_U2       = (const float*)d_in[6];
  const float* b_U2       = (const float*)d_in[7];
  const float* W_U1       = (const float*)d_in[8];
  const float* b_U1       = (const float*)d_in[9];

  const size_t SL = (size_t)Mrows * Hd;            // 8,388,608 ushorts
  // ws layout (61.4 MB total): AFa | AFb(NEI) | PIdx | panels | Apadh | Z
  ushort* AFa  = (ushort*)d_ws;
  ushort* AFb  = AFa + SL;
  uint*   PIdx = (uint*)(AFb + SL);
  ushort* w2h  = (ushort*)(PIdx + (size_t)Mrows * MNB);
  ushort* w1ah = w2h  + 256 * 256;
  ushort* w1bh = w1ah + 256 * 256;
  ushort* w2ch = w1bh + 256 * 256;
  ushort* w2cl = w2ch + Hd * Kpad;
  ushort* w1ch = w2cl + Hd * Kpad;
  ushort* w1cl = w1ch + Hd * Kpad;
  ushort* Apadh= w1cl + Hd * Kpad;
  ushort* Zbuf = Apadh + (size_t)Mrows * Kpad;

  ushort* Tbf = (ushort*)d_out;                    // d_out lo half: T (bf16)
  ushort* Pbf = Tbf + SL;                          // d_out hi half: P (bf16)

  const dim3 blk(256);
  const dim3 gTU(Mrows / 128, Hd / 64);            // (256, 4)
  const dim3 gG (Mrows / 128, Hd / 128);           // (256, 2)

  megaprep<<<S0 + S1 + S2 + S3 + S4, blk, 0, stream>>>(
      input_atom, input_bond, atom_graph, bond_graph, W_atom, W_U2, b_U2, W_U1,
      Apadh, Zbuf, PIdx, w2h, w1ah, w1bh, w2ch, w2cl, w1ch, w1cl);

  // ---- depth 0 (embed folded: T0 = Apad@Wcomb2, P0 = Apad@Wcomb1 + b_U1) ----
  {
    TUSegs t{};
    t.a[0] = Apadh; t.a[1] = Apadh;
    t.bt[0] = w2ch; t.bt[1] = w2cl;
    t.bp[0] = w1ch; t.bp[1] = w1cl;
    gemm_tu<2, Kpad><<<gTU, blk, 0, stream>>>(t, b_U1, Tbf, Pbf);
  }
  nei_z<<<Mrows / 8, blk, 0, stream>>>(Tbf, Zbuf, PIdx, num_nbs, AFb);
  {
    SegPtrs s{};
    s.a[0] = AFb; s.b[0] = w1bh;
    gemm_mfma<1, Hd, 2, true, false, true><<<gG, blk, 0, stream>>>(s, nullptr, Pbf, nullptr, AFa);
  }

  // ---- depth 1 ----
  {
    TUSegs t{};
    t.a[0] = AFa; t.bt[0] = w2h; t.bp[0] = w1ah;
    gemm_tu<1, Hd><<<gTU, blk, 0, stream>>>(t, b_U1, Tbf, Pbf);
  }
  nei_z<<<Mrows / 8, blk, 0, stream>>>(Tbf, Zbuf, PIdx, num_nbs, AFb);
  {
    SegPtrs s{};
    s.a[0] = AFb; s.b[0] = w1bh;
    gemm_mfma<1, Hd, 2, true, false, true><<<gG, blk, 0, stream>>>(s, nullptr, Pbf, nullptr, AFa);
  }

  // ---- depth 2 (exact fp32 output path, unfused) ----
  {
    SegPtrs s{};
    s.a[0] = AFa; s.b[0] = w2h;
    gemm_mfma<1, Hd, 2, false, false, false><<<gG, blk, 0, stream>>>(s, nullptr, nullptr, nullptr, Tbf);
  }
  nei_z<<<Mrows / 8, blk, 0, stream>>>(Tbf, Zbuf, PIdx, num_nbs, AFb);
  {
    SegPtrs s{};
    s.a[0] = AFa; s.a[1] = AFb;
    s.b[0] = w1ah; s.b[1] = w1bh;
    gemm_mfma<2, Hd, 0, true, true, false><<<gG, blk, 0, stream>>>(s, b_U1, nullptr, (float*)d_out, nullptr);
  }
  // d_out holds the final atom_features (fp32).
}

// Round 8
// 186.643 us; speedup vs baseline: 1.1055x; 1.1055x over previous
//
#include <hip/hip_runtime.h>

// Problem constants (WLN_Edit): B=64, N=512, NB=600, A=89, E=5, H=256, MAX_NB=10, DEPTH=3
constexpr int Bb   = 64;
constexpr int Nn   = 512;
constexpr int NBb  = 600;
constexpr int Ad   = 89;
constexpr int Ed   = 5;
constexpr int Hd   = 256;
constexpr int MNB  = 10;
constexpr int Mrows  = Bb * Nn;    // 32768
constexpr int NBrows = Bb * NBb;   // 38400
constexpr int Kpad   = 96;

typedef __bf16 bf16x8 __attribute__((ext_vector_type(8)));
typedef float  f32x4  __attribute__((ext_vector_type(4)));

typedef __attribute__((address_space(1))) const void gvoid_t;
typedef __attribute__((address_space(3))) void lvoid_t;

__device__ inline ushort bf_rne(float x) {
  unsigned u = __float_as_uint(x);
  unsigned r = (u + 0x7fffu + ((u >> 16) & 1u)) >> 16;
  return (ushort)r;
}
__device__ inline float bf_f(ushort h) { return __uint_as_float(((unsigned)h) << 16); }

// ---------------------------------------------------------------------------
// Mega-prep (NO LDS — round 7's shared array capped occupancy for all blocks):
//  S0: input_atom -> Apadh (single bf16, padded [32768][96])
//  S1: Z[b,i,h] = input_bond@W_U2[256:] + b_U2 (bf16)
//  S2: PIdx[m*10+k] = (ai<<16)|bi
//  S3: w2h/w1ah/w1bh: bf16 weight panels transposed [n][k]
//  S4L: wah/wal = W_atom transposed+split bf16 [256][96] (1 load/thread,
//       fully parallel — replaces the slow Wcomb dense-GEMM section)
// ---------------------------------------------------------------------------
constexpr int S0 = Mrows * Kpad / 256;   // 12288
constexpr int S1 = NBrows / 8;           // 4800
constexpr int S2 = Mrows * MNB / 256;    // 1280
constexpr int S3 = 256;
constexpr int S4L = Hd * Kpad / 256;     // 96

__global__ __launch_bounds__(256)
void megaprep(const float* __restrict__ input_atom, const float* __restrict__ input_bond,
              const int* __restrict__ atom_graph, const int* __restrict__ bond_graph,
              const float* __restrict__ W_atom, const float* __restrict__ W_U2,
              const float* __restrict__ b_U2, const float* __restrict__ W_U1,
              ushort* __restrict__ Apadh, ushort* __restrict__ Z, uint* __restrict__ PIdx,
              ushort* __restrict__ w2h, ushort* __restrict__ w1ah, ushort* __restrict__ w1bh,
              ushort* __restrict__ wah, ushort* __restrict__ wal) {
  const int blk = blockIdx.x;
  const int tid = threadIdx.x;
  if (blk < S0) {                                   // conv_atom
    const int e = blk * 256 + tid;
    const int m = e / Kpad, c = e - m * Kpad;
    Apadh[e] = bf_rne(c < Ad ? input_atom[(size_t)m * Ad + c] : 0.f);
  } else if (blk < S0 + S1) {                       // zprep
    const int r0 = (blk - S0) * 8;
    const int h = tid;
    float w[Ed];
#pragma unroll
    for (int e = 0; e < Ed; ++e) w[e] = W_U2[(size_t)(Hd + e) * Hd + h];
    const float b2 = b_U2[h];
#pragma unroll
    for (int j = 0; j < 8; ++j) {
      const int r = r0 + j;
      const float* bp = input_bond + (size_t)r * Ed;
      float d = b2;
#pragma unroll
      for (int e = 0; e < Ed; ++e) d = fmaf(bp[e], w[e], d);
      Z[(size_t)r * Hd + h] = bf_rne(d);
    }
  } else if (blk < S0 + S1 + S2) {                  // idxpack
    const int i = (blk - S0 - S1) * 256 + tid;
    const uint ai = (uint)atom_graph[(size_t)i * 2 + 1];
    const uint bi = (uint)bond_graph[(size_t)i * 2 + 1];
    PIdx[i] = (ai << 16) | bi;
  } else if (blk < S0 + S1 + S2 + S3) {             // transposed weight panels
    const int n = blk - S0 - S1 - S2;
    const int k = tid;
    const size_t o = (size_t)n * 256 + k;
    w2h[o]  = bf_rne(W_U2[(size_t)k * Hd + n]);
    w1ah[o] = bf_rne(W_U1[(size_t)k * Hd + n]);
    w1bh[o] = bf_rne(W_U1[(size_t)(k + 256) * Hd + n]);
  } else {                                          // S4L: W_atom^T split panels
    const int e = (blk - S0 - S1 - S2 - S3) * 256 + tid;   // e = n*96+k
    const int n = e / Kpad, k = e - n * Kpad;
    const float v = (k < Ad) ? W_atom[(size_t)k * Hd + n] : 0.f;
    const ushort h = bf_rne(v);
    wah[e] = h;
    wal[e] = bf_rne(v - bf_f(h));
  }
}

// ---------------------------------------------------------------------------
// Fused TU GEMM: T = sum_seg A@Bt^T (bf16 out), P = sum_seg A@Bp^T + b_U1 (bf16).
// BM=128, BN=64, BK=32, 4 waves, 2-phase double-buffered, 1 barrier/K-step.
// ---------------------------------------------------------------------------
struct TUSegs { const ushort* a[2]; const ushort* bt[2]; const ushort* bp[2]; };

template<int NSEG, int KD>
__global__ __launch_bounds__(256)
void gemm_tu(TUSegs segs, const float* __restrict__ bias,
             ushort* __restrict__ Tout, ushort* __restrict__ Pout) {
  constexpr int NK = KD / 32;
  constexpr int TS = NSEG * NK;
  __shared__ ushort As[2][4096];
  __shared__ ushort Bt[2][2048];
  __shared__ ushort Bp[2][2048];
  const int tid  = threadIdx.x;
  const int lane = tid & 63;
  const int w    = tid >> 6;
  const int wr   = w >> 1, wc = w & 1;
  const int m0   = blockIdx.x * 128;
  const int n0   = blockIdx.y * 64;
  const int arow = tid >> 2;
  const int acol = (tid & 3) * 8;
  const int fr   = lane & 15;
  const int fq   = lane >> 4;

  f32x4 accT[4][2] = {};
  f32x4 accP[4][2] = {};

  auto stage = [&](const ushort* Aseg, const ushort* Bts, const ushort* Bps,
                   int kk, int db) {
#pragma unroll
    for (int i = 0; i < 2; ++i) {
      const ushort* ga = Aseg + (size_t)(m0 + arow + 64 * i) * KD + kk + acol;
      __builtin_amdgcn_global_load_lds((gvoid_t*)ga,
          (lvoid_t*)(&As[db][i * 2048 + w * 512]), 16, 0, 0);
    }
    const ushort* gt = Bts + (size_t)(n0 + arow) * KD + kk + acol;
    __builtin_amdgcn_global_load_lds((gvoid_t*)gt,
        (lvoid_t*)(&Bt[db][w * 512]), 16, 0, 0);
    const ushort* gp = Bps + (size_t)(n0 + arow) * KD + kk + acol;
    __builtin_amdgcn_global_load_lds((gvoid_t*)gp,
        (lvoid_t*)(&Bp[db][w * 512]), 16, 0, 0);
  };

  stage(segs.a[0], segs.bt[0], segs.bp[0], 0, 0);
  __syncthreads();

#pragma unroll
  for (int ts = 0; ts < TS; ++ts) {
    const int db = ts & 1;
    if (ts + 1 < TS) {
      const int s2 = (ts + 1) / NK;
      const int k2 = (ts + 1) % NK;
      stage(segs.a[s2], segs.bt[s2], segs.bp[s2], k2 * 32, db ^ 1);
    }
    bf16x8 bt_[2], bp_[2];
#pragma unroll
    for (int nf = 0; nf < 2; ++nf) {
      bt_[nf] = *reinterpret_cast<const bf16x8*>(&Bt[db][(wc * 32 + nf * 16 + fr) * 32 + fq * 8]);
      bp_[nf] = *reinterpret_cast<const bf16x8*>(&Bp[db][(wc * 32 + nf * 16 + fr) * 32 + fq * 8]);
    }
#pragma unroll
    for (int mf = 0; mf < 4; ++mf) {
      bf16x8 af = *reinterpret_cast<const bf16x8*>(&As[db][(wr * 64 + mf * 16 + fr) * 32 + fq * 8]);
#pragma unroll
      for (int nf = 0; nf < 2; ++nf) {
        accT[mf][nf] = __builtin_amdgcn_mfma_f32_16x16x32_bf16(af, bt_[nf], accT[mf][nf], 0, 0, 0);
        accP[mf][nf] = __builtin_amdgcn_mfma_f32_16x16x32_bf16(af, bp_[nf], accP[mf][nf], 0, 0, 0);
      }
    }
    __syncthreads();
  }

#pragma unroll
  for (int mf = 0; mf < 4; ++mf) {
#pragma unroll
    for (int nf = 0; nf < 2; ++nf) {
      const int col = n0 + wc * 32 + nf * 16 + fr;
      const float bv = bias[col];
#pragma unroll
      for (int r = 0; r < 4; ++r) {
        const int row = m0 + wr * 64 + mf * 16 + fq * 4 + r;
        Tout[(size_t)row * Hd + col] = bf_rne(accT[mf][nf][r]);
        Pout[(size_t)row * Hd + col] = bf_rne(accP[mf][nf][r] + bv);
      }
    }
  }
}

// ---------------------------------------------------------------------------
// MFMA GEMM (128x128, 4 waves): C = op( sum_seg A_seg @ B_seg^T [+ Pin] )
// OUTMODE: 0 = fp32 to Cf; 2 = bf16 to Chi.  CLOAD: add bf16 Pin tile.
// ---------------------------------------------------------------------------
struct SegPtrs { const ushort* a[2]; const ushort* b[2]; };

template<int NSEG, int KD, int OUTMODE, bool RELU, bool BIAS, bool CLOAD>
__global__ __launch_bounds__(256)
void gemm_mfma(SegPtrs segs, const float* __restrict__ bias,
               const ushort* __restrict__ Pin,
               float* __restrict__ Cf, ushort* __restrict__ Chi) {
  constexpr int NK = KD / 32;
  constexpr int TS = NSEG * NK;
  __shared__ ushort As[2][4096];
  __shared__ ushort Bs[2][4096];
  const int tid  = threadIdx.x;
  const int lane = tid & 63;
  const int w    = tid >> 6;
  const int wr   = w >> 1, wc = w & 1;
  const int m0   = blockIdx.x * 128;
  const int n0   = blockIdx.y * 128;
  const int arow = tid >> 2;
  const int acol = (tid & 3) * 8;
  const int fr   = lane & 15;
  const int fq   = lane >> 4;

  f32x4 acc[4][4] = {};

  auto stage = [&](const ushort* Aseg, const ushort* Bseg, int kk, int db) {
#pragma unroll
    for (int i = 0; i < 2; ++i) {
      const ushort* ga = Aseg + (size_t)(m0 + arow + 64 * i) * KD + kk + acol;
      const ushort* gb = Bseg + (size_t)(n0 + arow + 64 * i) * KD + kk + acol;
      __builtin_amdgcn_global_load_lds((gvoid_t*)ga,
          (lvoid_t*)(&As[db][i * 2048 + w * 512]), 16, 0, 0);
      __builtin_amdgcn_global_load_lds((gvoid_t*)gb,
          (lvoid_t*)(&Bs[db][i * 2048 + w * 512]), 16, 0, 0);
    }
  };

  stage(segs.a[0], segs.b[0], 0, 0);
  __syncthreads();

#pragma unroll
  for (int ts = 0; ts < TS; ++ts) {
    const int db = ts & 1;
    if (ts + 1 < TS) {
      const int s2 = (ts + 1) / NK;
      const int k2 = (ts + 1) % NK;
      stage(segs.a[s2], segs.b[s2], k2 * 32, db ^ 1);
    }
    bf16x8 bfr[4];
#pragma unroll
    for (int nf = 0; nf < 4; ++nf)
      bfr[nf] = *reinterpret_cast<const bf16x8*>(&Bs[db][(wc * 64 + nf * 16 + fr) * 32 + fq * 8]);
#pragma unroll
    for (int mf = 0; mf < 4; ++mf) {
      bf16x8 af = *reinterpret_cast<const bf16x8*>(&As[db][(wr * 64 + mf * 16 + fr) * 32 + fq * 8]);
#pragma unroll
      for (int nf = 0; nf < 4; ++nf)
        acc[mf][nf] = __builtin_amdgcn_mfma_f32_16x16x32_bf16(af, bfr[nf], acc[mf][nf], 0, 0, 0);
    }
    __syncthreads();
  }

#pragma unroll
  for (int mf = 0; mf < 4; ++mf) {
#pragma unroll
    for (int nf = 0; nf < 4; ++nf) {
      const int col = n0 + wc * 64 + nf * 16 + fr;
      float bv = 0.f;
      if constexpr (BIAS) bv = bias[col];
#pragma unroll
      for (int r = 0; r < 4; ++r) {
        const int row = m0 + wr * 64 + mf * 16 + fq * 4 + r;
        float v = acc[mf][nf][r] + bv;
        if constexpr (CLOAD) v += bf_f(Pin[(size_t)row * Hd + col]);
        if constexpr (RELU) v = fmaxf(v, 0.f);
        const size_t o = (size_t)row * Hd + col;
        if constexpr (OUTMODE == 0) Cf[o] = v;
        else                        Chi[o] = bf_rne(v);
      }
    }
  }
}

// ---------------------------------------------------------------------------
// nei: NEI[m,h] = sum_{k<nn} relu(T[ai[k]] + Z[bi[k]]), packed indices,
// h-oct threads (uint4 loads), 5+5 neighbor chunks. 8 rows/block.
// ---------------------------------------------------------------------------
__global__ __launch_bounds__(256)
void nei_z(const ushort* __restrict__ T, const ushort* __restrict__ Z,
           const uint* __restrict__ PIdx, const int* __restrict__ num_nbs,
           ushort* __restrict__ NEI) {
  const int ho = threadIdx.x & 31;
  const int rp = threadIdx.x >> 5;
  int bid = blockIdx.x;
  bid = (bid & 7) * (gridDim.x >> 3) + (bid >> 3);   // XCD swizzle (4096%8==0)
  const int m = bid * 8 + rp;
  const int b = m >> 9;
  const int h0 = ho * 8;
  const int nn = num_nbs[m];

  uint pk[MNB];
#pragma unroll
  for (int q = 0; q < 5; ++q) {
    const uint2 u = *reinterpret_cast<const uint2*>(&PIdx[(size_t)m * MNB + q * 2]);
    pk[q * 2] = u.x; pk[q * 2 + 1] = u.y;
  }
  int ai[MNB], bi[MNB];
#pragma unroll
  for (int k = 0; k < MNB; ++k) { ai[k] = (int)(pk[k] >> 16); bi[k] = (int)(pk[k] & 0xffffu); }
#pragma unroll
  for (int k = 1; k < MNB; ++k) {
    ai[k] = (k < nn) ? ai[k] : ai[0];
    bi[k] = (k < nn) ? bi[k] : bi[0];
  }

  float acc[8] = {};
#pragma unroll
  for (int ch = 0; ch < 2; ++ch) {
    uint4 tv[5], zv[5];
#pragma unroll
    for (int k5 = 0; k5 < 5; ++k5) {
      const int k = ch * 5 + k5;
      tv[k5] = *reinterpret_cast<const uint4*>(&T[(((size_t)b << 9) + ai[k]) * Hd + h0]);
      zv[k5] = *reinterpret_cast<const uint4*>(&Z[((size_t)b * NBb + bi[k]) * Hd + h0]);
    }
#pragma unroll
    for (int k5 = 0; k5 < 5; ++k5) {
      const int k = ch * 5 + k5;
      const uint tw[4] = {tv[k5].x, tv[k5].y, tv[k5].z, tv[k5].w};
      const uint zw[4] = {zv[k5].x, zv[k5].y, zv[k5].z, zv[k5].w};
      if (k < nn) {
#pragma unroll
        for (int q = 0; q < 4; ++q) {
          acc[q * 2]     += fmaxf(__uint_as_float(tw[q] << 16) + __uint_as_float(zw[q] << 16), 0.f);
          acc[q * 2 + 1] += fmaxf(__uint_as_float(tw[q] & 0xffff0000u) + __uint_as_float(zw[q] & 0xffff0000u), 0.f);
        }
      }
    }
  }
  uint4 o;
  o.x = (uint)bf_rne(acc[0]) | ((uint)bf_rne(acc[1]) << 16);
  o.y = (uint)bf_rne(acc[2]) | ((uint)bf_rne(acc[3]) << 16);
  o.z = (uint)bf_rne(acc[4]) | ((uint)bf_rne(acc[5]) << 16);
  o.w = (uint)bf_rne(acc[6]) | ((uint)bf_rne(acc[7]) << 16);
  *reinterpret_cast<uint4*>(&NEI[(size_t)m * Hd + h0]) = o;
}

extern "C" void kernel_launch(void* const* d_in, const int* in_sizes, int n_in,
                              void* d_out, int out_size, void* d_ws, size_t ws_size,
                              hipStream_t stream) {
  const float* input_atom = (const float*)d_in[0];
  const float* input_bond = (const float*)d_in[1];
  const int*   atom_graph = (const int*)d_in[2];
  const int*   bond_graph = (const int*)d_in[3];
  const int*   num_nbs    = (const int*)d_in[4];
  const float* W_atom     = (const float*)d_in[5];
  const float* W_U2       = (const float*)d_in[6];
  const float* b_U2       = (const float*)d_in[7];
  const float* W_U1       = (const float*)d_in[8];
  const float* b_U1       = (const float*)d_in[9];

  const size_t SL = (size_t)Mrows * Hd;            // 8,388,608 ushorts
  // ws layout (~61.3 MB): AFa | AFb(NEI) | PIdx | panels | wah/wal | Apadh | Z
  ushort* AFa  = (ushort*)d_ws;
  ushort* AFb  = AFa + SL;
  uint*   PIdx = (uint*)(AFb + SL);
  ushort* w2h  = (ushort*)(PIdx + (size_t)Mrows * MNB);
  ushort* w1ah = w2h  + 256 * 256;
  ushort* w1bh = w1ah + 256 * 256;
  ushort* wah  = w1bh + 256 * 256;
  ushort* wal  = wah  + Hd * Kpad;
  ushort* Apadh= wal  + Hd * Kpad;
  ushort* Zbuf = Apadh + (size_t)Mrows * Kpad;

  ushort* Tbf = (ushort*)d_out;                    // d_out lo half: T (bf16)
  ushort* Pbf = Tbf + SL;                          // d_out hi half: P (bf16)

  const dim3 blk(256);
  const dim3 gTU(Mrows / 128, Hd / 64);            // (256, 4)
  const dim3 gG (Mrows / 128, Hd / 128);           // (256, 2)

  megaprep<<<S0 + S1 + S2 + S3 + S4L, blk, 0, stream>>>(
      input_atom, input_bond, atom_graph, bond_graph, W_atom, W_U2, b_U2, W_U1,
      Apadh, Zbuf, PIdx, w2h, w1ah, w1bh, wah, wal);

  // embed: AF0 = Apadh @ {wah + wal}  (2 segs, K=96, MFMA) -> AFa (bf16)
  {
    SegPtrs se{};
    se.a[0] = Apadh; se.a[1] = Apadh;
    se.b[0] = wah;   se.b[1] = wal;
    gemm_mfma<2, Kpad, 2, false, false, false><<<gG, blk, 0, stream>>>(se, nullptr, nullptr, nullptr, AFa);
  }

  // ---- depths 0 and 1 (fused TU + nei + CLOAD-GEMM, bf16 state) ----
  for (int d = 0; d < 2; ++d) {
    TUSegs t{};
    t.a[0] = AFa; t.bt[0] = w2h; t.bp[0] = w1ah;
    gemm_tu<1, Hd><<<gTU, blk, 0, stream>>>(t, b_U1, Tbf, Pbf);

    nei_z<<<Mrows / 8, blk, 0, stream>>>(Tbf, Zbuf, PIdx, num_nbs, AFb);

    SegPtrs s{};
    s.a[0] = AFb; s.b[0] = w1bh;
    gemm_mfma<1, Hd, 2, true, false, true><<<gG, blk, 0, stream>>>(s, nullptr, Pbf, nullptr, AFa);
  }

  // ---- depth 2 (exact fp32 output path, unfused) ----
  {
    SegPtrs s{};
    s.a[0] = AFa; s.b[0] = w2h;
    gemm_mfma<1, Hd, 2, false, false, false><<<gG, blk, 0, stream>>>(s, nullptr, nullptr, nullptr, Tbf);
  }
  nei_z<<<Mrows / 8, blk, 0, stream>>>(Tbf, Zbuf, PIdx, num_nbs, AFb);
  {
    SegPtrs s{};
    s.a[0] = AFa; s.a[1] = AFb;
    s.b[0] = w1ah; s.b[1] = w1bh;
    gemm_mfma<2, Hd, 0, true, true, false><<<gG, blk, 0, stream>>>(s, b_U1, nullptr, (float*)d_out, nullptr);
  }
  // d_out holds the final atom_features (fp32).
}

// Round 9
// 179.699 us; speedup vs baseline: 1.1482x; 1.0386x over previous
//
#include <hip/hip_runtime.h>

// Problem constants (WLN_Edit): B=64, N=512, NB=600, A=89, E=5, H=256, MAX_NB=10, DEPTH=3
constexpr int Bb   = 64;
constexpr int Nn   = 512;
constexpr int NBb  = 600;
constexpr int Ad   = 89;
constexpr int Ed   = 5;
constexpr int Hd   = 256;
constexpr int MNB  = 10;
constexpr int Mrows  = Bb * Nn;    // 32768
constexpr int NBrows = Bb * NBb;   // 38400
constexpr int Kpad   = 96;

typedef __bf16 bf16x8 __attribute__((ext_vector_type(8)));
typedef float  f32x4  __attribute__((ext_vector_type(4)));

typedef __attribute__((address_space(1))) const void gvoid_t;
typedef __attribute__((address_space(3))) void lvoid_t;

__device__ inline ushort bf_rne(float x) {
  unsigned u = __float_as_uint(x);
  unsigned r = (u + 0x7fffu + ((u >> 16) & 1u)) >> 16;
  return (ushort)r;
}
__device__ inline float bf_f(ushort h) { return __uint_as_float(((unsigned)h) << 16); }

// ---------------------------------------------------------------------------
// Mega-prep (no LDS):
//  S0: input_atom -> Apadh (bf16, padded [32768][96])
//  S1: Z = input_bond@W_U2[256:] + b_U2 (bf16)
//  S2: PIdx[m*10+k] = (ai<<16)|bi
//  S3: w2h/w1ah/w1bh transposed bf16 panels
//  S4L: wah = W_atom transposed bf16 [256][96] (single panel; lo-panel dropped —
//       AF0 quant is damped ~0.16x per downstream GEMM, ~3e-5 at output)
// ---------------------------------------------------------------------------
constexpr int S0 = Mrows * Kpad / 256;   // 12288
constexpr int S1 = NBrows / 8;           // 4800
constexpr int S2 = Mrows * MNB / 256;    // 1280
constexpr int S3 = 256;
constexpr int S4L = Hd * Kpad / 256;     // 96

__global__ __launch_bounds__(256)
void megaprep(const float* __restrict__ input_atom, const float* __restrict__ input_bond,
              const int* __restrict__ atom_graph, const int* __restrict__ bond_graph,
              const float* __restrict__ W_atom, const float* __restrict__ W_U2,
              const float* __restrict__ b_U2, const float* __restrict__ W_U1,
              ushort* __restrict__ Apadh, ushort* __restrict__ Z, uint* __restrict__ PIdx,
              ushort* __restrict__ w2h, ushort* __restrict__ w1ah, ushort* __restrict__ w1bh,
              ushort* __restrict__ wah) {
  const int blk = blockIdx.x;
  const int tid = threadIdx.x;
  if (blk < S0) {                                   // conv_atom
    const int e = blk * 256 + tid;
    const int m = e / Kpad, c = e - m * Kpad;
    Apadh[e] = bf_rne(c < Ad ? input_atom[(size_t)m * Ad + c] : 0.f);
  } else if (blk < S0 + S1) {                       // zprep
    const int r0 = (blk - S0) * 8;
    const int h = tid;
    float w[Ed];
#pragma unroll
    for (int e = 0; e < Ed; ++e) w[e] = W_U2[(size_t)(Hd + e) * Hd + h];
    const float b2 = b_U2[h];
#pragma unroll
    for (int j = 0; j < 8; ++j) {
      const int r = r0 + j;
      const float* bp = input_bond + (size_t)r * Ed;
      float d = b2;
#pragma unroll
      for (int e = 0; e < Ed; ++e) d = fmaf(bp[e], w[e], d);
      Z[(size_t)r * Hd + h] = bf_rne(d);
    }
  } else if (blk < S0 + S1 + S2) {                  // idxpack
    const int i = (blk - S0 - S1) * 256 + tid;
    const uint ai = (uint)atom_graph[(size_t)i * 2 + 1];
    const uint bi = (uint)bond_graph[(size_t)i * 2 + 1];
    PIdx[i] = (ai << 16) | bi;
  } else if (blk < S0 + S1 + S2 + S3) {             // transposed weight panels
    const int n = blk - S0 - S1 - S2;
    const int k = tid;
    const size_t o = (size_t)n * 256 + k;
    w2h[o]  = bf_rne(W_U2[(size_t)k * Hd + n]);
    w1ah[o] = bf_rne(W_U1[(size_t)k * Hd + n]);
    w1bh[o] = bf_rne(W_U1[(size_t)(k + 256) * Hd + n]);
  } else {                                          // S4L: W_atom^T panel
    const int e = (blk - S0 - S1 - S2 - S3) * 256 + tid;   // e = n*96+k
    const int n = e / Kpad, k = e - n * Kpad;
    wah[e] = bf_rne((k < Ad) ? W_atom[(size_t)k * Hd + n] : 0.f);
  }
}

// ---------------------------------------------------------------------------
// Fused TU GEMM, 128x128 tile: T = A@Bt^T (bf16), P = A@Bp^T + b_U1 (bf16).
// BK=32, 4 waves (each 64x64 of BOTH outputs: 32 MFMA / 12 ds_read_b128 per
// K-step), 2-phase double-buffered, 48 KB LDS, 1 barrier/K-step.
// ---------------------------------------------------------------------------
struct TUSegs { const ushort* a[2]; const ushort* bt[2]; const ushort* bp[2]; };

template<int NSEG, int KD>
__global__ __launch_bounds__(256)
void gemm_tu(TUSegs segs, const float* __restrict__ bias,
             ushort* __restrict__ Tout, ushort* __restrict__ Pout) {
  constexpr int NK = KD / 32;
  constexpr int TS = NSEG * NK;
  __shared__ ushort As[2][4096];
  __shared__ ushort Bt[2][4096];
  __shared__ ushort Bp[2][4096];
  const int tid  = threadIdx.x;
  const int lane = tid & 63;
  const int w    = tid >> 6;
  const int wr   = w >> 1, wc = w & 1;
  const int m0   = blockIdx.x * 128;
  const int n0   = blockIdx.y * 128;
  const int arow = tid >> 2;
  const int acol = (tid & 3) * 8;
  const int fr   = lane & 15;
  const int fq   = lane >> 4;

  f32x4 accT[4][4] = {};
  f32x4 accP[4][4] = {};

  auto stage = [&](const ushort* Aseg, const ushort* Bts, const ushort* Bps,
                   int kk, int db) {
#pragma unroll
    for (int i = 0; i < 2; ++i) {
      const ushort* ga = Aseg + (size_t)(m0 + arow + 64 * i) * KD + kk + acol;
      __builtin_amdgcn_global_load_lds((gvoid_t*)ga,
          (lvoid_t*)(&As[db][i * 2048 + w * 512]), 16, 0, 0);
      const ushort* gt = Bts + (size_t)(n0 + arow + 64 * i) * KD + kk + acol;
      __builtin_amdgcn_global_load_lds((gvoid_t*)gt,
          (lvoid_t*)(&Bt[db][i * 2048 + w * 512]), 16, 0, 0);
      const ushort* gp = Bps + (size_t)(n0 + arow + 64 * i) * KD + kk + acol;
      __builtin_amdgcn_global_load_lds((gvoid_t*)gp,
          (lvoid_t*)(&Bp[db][i * 2048 + w * 512]), 16, 0, 0);
    }
  };

  stage(segs.a[0], segs.bt[0], segs.bp[0], 0, 0);
  __syncthreads();

#pragma unroll
  for (int ts = 0; ts < TS; ++ts) {
    const int db = ts & 1;
    if (ts + 1 < TS) {
      const int s2 = (ts + 1) / NK;
      const int k2 = (ts + 1) % NK;
      stage(segs.a[s2], segs.bt[s2], segs.bp[s2], k2 * 32, db ^ 1);
    }
    bf16x8 bt_[4], bp_[4];
#pragma unroll
    for (int nf = 0; nf < 4; ++nf) {
      bt_[nf] = *reinterpret_cast<const bf16x8*>(&Bt[db][(wc * 64 + nf * 16 + fr) * 32 + fq * 8]);
      bp_[nf] = *reinterpret_cast<const bf16x8*>(&Bp[db][(wc * 64 + nf * 16 + fr) * 32 + fq * 8]);
    }
#pragma unroll
    for (int mf = 0; mf < 4; ++mf) {
      bf16x8 af = *reinterpret_cast<const bf16x8*>(&As[db][(wr * 64 + mf * 16 + fr) * 32 + fq * 8]);
#pragma unroll
      for (int nf = 0; nf < 4; ++nf) {
        accT[mf][nf] = __builtin_amdgcn_mfma_f32_16x16x32_bf16(af, bt_[nf], accT[mf][nf], 0, 0, 0);
        accP[mf][nf] = __builtin_amdgcn_mfma_f32_16x16x32_bf16(af, bp_[nf], accP[mf][nf], 0, 0, 0);
      }
    }
    __syncthreads();
  }

#pragma unroll
  for (int mf = 0; mf < 4; ++mf) {
#pragma unroll
    for (int nf = 0; nf < 4; ++nf) {
      const int col = n0 + wc * 64 + nf * 16 + fr;
      const float bv = bias[col];
#pragma unroll
      for (int r = 0; r < 4; ++r) {
        const int row = m0 + wr * 64 + mf * 16 + fq * 4 + r;
        Tout[(size_t)row * Hd + col] = bf_rne(accT[mf][nf][r]);
        Pout[(size_t)row * Hd + col] = bf_rne(accP[mf][nf][r] + bv);
      }
    }
  }
}

// ---------------------------------------------------------------------------
// MFMA GEMM (128x128, 4 waves): C = op( sum_seg A_seg @ B_seg^T [+ Pin] )
// OUTMODE: 0 = fp32 to Cf; 2 = bf16 to Chi.  CLOAD: add bf16 Pin tile.
// ---------------------------------------------------------------------------
struct SegPtrs { const ushort* a[2]; const ushort* b[2]; };

template<int NSEG, int KD, int OUTMODE, bool RELU, bool BIAS, bool CLOAD>
__global__ __launch_bounds__(256)
void gemm_mfma(SegPtrs segs, const float* __restrict__ bias,
               const ushort* __restrict__ Pin,
               float* __restrict__ Cf, ushort* __restrict__ Chi) {
  constexpr int NK = KD / 32;
  constexpr int TS = NSEG * NK;
  __shared__ ushort As[2][4096];
  __shared__ ushort Bs[2][4096];
  const int tid  = threadIdx.x;
  const int lane = tid & 63;
  const int w    = tid >> 6;
  const int wr   = w >> 1, wc = w & 1;
  const int m0   = blockIdx.x * 128;
  const int n0   = blockIdx.y * 128;
  const int arow = tid >> 2;
  const int acol = (tid & 3) * 8;
  const int fr   = lane & 15;
  const int fq   = lane >> 4;

  f32x4 acc[4][4] = {};

  auto stage = [&](const ushort* Aseg, const ushort* Bseg, int kk, int db) {
#pragma unroll
    for (int i = 0; i < 2; ++i) {
      const ushort* ga = Aseg + (size_t)(m0 + arow + 64 * i) * KD + kk + acol;
      const ushort* gb = Bseg + (size_t)(n0 + arow + 64 * i) * KD + kk + acol;
      __builtin_amdgcn_global_load_lds((gvoid_t*)ga,
          (lvoid_t*)(&As[db][i * 2048 + w * 512]), 16, 0, 0);
      __builtin_amdgcn_global_load_lds((gvoid_t*)gb,
          (lvoid_t*)(&Bs[db][i * 2048 + w * 512]), 16, 0, 0);
    }
  };

  stage(segs.a[0], segs.b[0], 0, 0);
  __syncthreads();

#pragma unroll
  for (int ts = 0; ts < TS; ++ts) {
    const int db = ts & 1;
    if (ts + 1 < TS) {
      const int s2 = (ts + 1) / NK;
      const int k2 = (ts + 1) % NK;
      stage(segs.a[s2], segs.b[s2], k2 * 32, db ^ 1);
    }
    bf16x8 bfr[4];
#pragma unroll
    for (int nf = 0; nf < 4; ++nf)
      bfr[nf] = *reinterpret_cast<const bf16x8*>(&Bs[db][(wc * 64 + nf * 16 + fr) * 32 + fq * 8]);
#pragma unroll
    for (int mf = 0; mf < 4; ++mf) {
      bf16x8 af = *reinterpret_cast<const bf16x8*>(&As[db][(wr * 64 + mf * 16 + fr) * 32 + fq * 8]);
#pragma unroll
      for (int nf = 0; nf < 4; ++nf)
        acc[mf][nf] = __builtin_amdgcn_mfma_f32_16x16x32_bf16(af, bfr[nf], acc[mf][nf], 0, 0, 0);
    }
    __syncthreads();
  }

#pragma unroll
  for (int mf = 0; mf < 4; ++mf) {
#pragma unroll
    for (int nf = 0; nf < 4; ++nf) {
      const int col = n0 + wc * 64 + nf * 16 + fr;
      float bv = 0.f;
      if constexpr (BIAS) bv = bias[col];
#pragma unroll
      for (int r = 0; r < 4; ++r) {
        const int row = m0 + wr * 64 + mf * 16 + fq * 4 + r;
        float v = acc[mf][nf][r] + bv;
        if constexpr (CLOAD) v += bf_f(Pin[(size_t)row * Hd + col]);
        if constexpr (RELU) v = fmaxf(v, 0.f);
        const size_t o = (size_t)row * Hd + col;
        if constexpr (OUTMODE == 0) Cf[o] = v;
        else                        Chi[o] = bf_rne(v);
      }
    }
  }
}

// ---------------------------------------------------------------------------
// nei: NEI[m,h] = sum_{k<nn} relu(T[ai[k]] + Z[bi[k]]), packed indices,
// h-oct threads (uint4 loads), 5+5 neighbor chunks. 8 rows/block.
// ---------------------------------------------------------------------------
__global__ __launch_bounds__(256)
void nei_z(const ushort* __restrict__ T, const ushort* __restrict__ Z,
           const uint* __restrict__ PIdx, const int* __restrict__ num_nbs,
           ushort* __restrict__ NEI) {
  const int ho = threadIdx.x & 31;
  const int rp = threadIdx.x >> 5;
  int bid = blockIdx.x;
  bid = (bid & 7) * (gridDim.x >> 3) + (bid >> 3);   // XCD swizzle (4096%8==0)
  const int m = bid * 8 + rp;
  const int b = m >> 9;
  const int h0 = ho * 8;
  const int nn = num_nbs[m];

  uint pk[MNB];
#pragma unroll
  for (int q = 0; q < 5; ++q) {
    const uint2 u = *reinterpret_cast<const uint2*>(&PIdx[(size_t)m * MNB + q * 2]);
    pk[q * 2] = u.x; pk[q * 2 + 1] = u.y;
  }
  int ai[MNB], bi[MNB];
#pragma unroll
  for (int k = 0; k < MNB; ++k) { ai[k] = (int)(pk[k] >> 16); bi[k] = (int)(pk[k] & 0xffffu); }
#pragma unroll
  for (int k = 1; k < MNB; ++k) {
    ai[k] = (k < nn) ? ai[k] : ai[0];
    bi[k] = (k < nn) ? bi[k] : bi[0];
  }

  float acc[8] = {};
#pragma unroll
  for (int ch = 0; ch < 2; ++ch) {
    uint4 tv[5], zv[5];
#pragma unroll
    for (int k5 = 0; k5 < 5; ++k5) {
      const int k = ch * 5 + k5;
      tv[k5] = *reinterpret_cast<const uint4*>(&T[(((size_t)b << 9) + ai[k]) * Hd + h0]);
      zv[k5] = *reinterpret_cast<const uint4*>(&Z[((size_t)b * NBb + bi[k]) * Hd + h0]);
    }
#pragma unroll
    for (int k5 = 0; k5 < 5; ++k5) {
      const int k = ch * 5 + k5;
      const uint tw[4] = {tv[k5].x, tv[k5].y, tv[k5].z, tv[k5].w};
      const uint zw[4] = {zv[k5].x, zv[k5].y, zv[k5].z, zv[k5].w};
      if (k < nn) {
#pragma unroll
        for (int q = 0; q < 4; ++q) {
          acc[q * 2]     += fmaxf(__uint_as_float(tw[q] << 16) + __uint_as_float(zw[q] << 16), 0.f);
          acc[q * 2 + 1] += fmaxf(__uint_as_float(tw[q] & 0xffff0000u) + __uint_as_float(zw[q] & 0xffff0000u), 0.f);
        }
      }
    }
  }
  uint4 o;
  o.x = (uint)bf_rne(acc[0]) | ((uint)bf_rne(acc[1]) << 16);
  o.y = (uint)bf_rne(acc[2]) | ((uint)bf_rne(acc[3]) << 16);
  o.z = (uint)bf_rne(acc[4]) | ((uint)bf_rne(acc[5]) << 16);
  o.w = (uint)bf_rne(acc[6]) | ((uint)bf_rne(acc[7]) << 16);
  *reinterpret_cast<uint4*>(&NEI[(size_t)m * Hd + h0]) = o;
}

extern "C" void kernel_launch(void* const* d_in, const int* in_sizes, int n_in,
                              void* d_out, int out_size, void* d_ws, size_t ws_size,
                              hipStream_t stream) {
  const float* input_atom = (const float*)d_in[0];
  const float* input_bond = (const float*)d_in[1];
  const int*   atom_graph = (const int*)d_in[2];
  const int*   bond_graph = (const int*)d_in[3];
  const int*   num_nbs    = (const int*)d_in[4];
  const float* W_atom     = (const float*)d_in[5];
  const float* W_U2       = (const float*)d_in[6];
  const float* b_U2       = (const float*)d_in[7];
  const float* W_U1       = (const float*)d_in[8];
  const float* b_U1       = (const float*)d_in[9];

  const size_t SL = (size_t)Mrows * Hd;            // 8,388,608 ushorts
  // ws layout (~61.3 MB): AFa | AFb(NEI) | PIdx | panels | wah | Apadh | Z
  ushort* AFa  = (ushort*)d_ws;
  ushort* AFb  = AFa + SL;
  uint*   PIdx = (uint*)(AFb + SL);
  ushort* w2h  = (ushort*)(PIdx + (size_t)Mrows * MNB);
  ushort* w1ah = w2h  + 256 * 256;
  ushort* w1bh = w1ah + 256 * 256;
  ushort* wah  = w1bh + 256 * 256;
  ushort* Apadh= wah  + Hd * Kpad;
  ushort* Zbuf = Apadh + (size_t)Mrows * Kpad;

  ushort* Tbf = (ushort*)d_out;                    // d_out lo half: T (bf16)
  ushort* Pbf = Tbf + SL;                          // d_out hi half: P (bf16)

  const dim3 blk(256);
  const dim3 gG(Mrows / 128, Hd / 128);            // (256, 2)

  megaprep<<<S0 + S1 + S2 + S3 + S4L, blk, 0, stream>>>(
      input_atom, input_bond, atom_graph, bond_graph, W_atom, W_U2, b_U2, W_U1,
      Apadh, Zbuf, PIdx, w2h, w1ah, w1bh, wah);

  // embed: AF0 = Apadh @ wah^T  (1 seg, K=96, MFMA) -> AFa (bf16)
  {
    SegPtrs se{};
    se.a[0] = Apadh;
    se.b[0] = wah;
    gemm_mfma<1, Kpad, 2, false, false, false><<<gG, blk, 0, stream>>>(se, nullptr, nullptr, nullptr, AFa);
  }

  // ---- depths 0 and 1 (fused TU + nei + CLOAD-GEMM, bf16 state) ----
  for (int d = 0; d < 2; ++d) {
    TUSegs t{};
    t.a[0] = AFa; t.bt[0] = w2h; t.bp[0] = w1ah;
    gemm_tu<1, Hd><<<gG, blk, 0, stream>>>(t, b_U1, Tbf, Pbf);

    nei_z<<<Mrows / 8, blk, 0, stream>>>(Tbf, Zbuf, PIdx, num_nbs, AFb);

    SegPtrs s{};
    s.a[0] = AFb; s.b[0] = w1bh;
    gemm_mfma<1, Hd, 2, true, false, true><<<gG, blk, 0, stream>>>(s, nullptr, Pbf, nullptr, AFa);
  }

  // ---- depth 2 (exact fp32 output path, unfused) ----
  {
    SegPtrs s{};
    s.a[0] = AFa; s.b[0] = w2h;
    gemm_mfma<1, Hd, 2, false, false, false><<<gG, blk, 0, stream>>>(s, nullptr, nullptr, nullptr, Tbf);
  }
  nei_z<<<Mrows / 8, blk, 0, stream>>>(Tbf, Zbuf, PIdx, num_nbs, AFb);
  {
    SegPtrs s{};
    s.a[0] = AFa; s.a[1] = AFb;
    s.b[0] = w1ah; s.b[1] = w1bh;
    gemm_mfma<2, Hd, 0, true, true, false><<<gG, blk, 0, stream>>>(s, b_U1, nullptr, (float*)d_out, nullptr);
  }
  // d_out holds the final atom_features (fp32).
}